// Round 17
// baseline (117.541 us; speedup 1.0000x reference)
//
#include <hip/hip_runtime.h>
#include <math.h>

#define NN   8192
#define FF   256
#define FF1  64
#define CAP  256   // max edges kept per row (mean 82, std 9 -> 19 sigma)

// ---------------------------------------------------------------------------
// R10 kernels byte-identical; k1 and k3 are each launched TWICE this round
// (both idempotent) to measure their individual costs: Δdur = k1 + k3.
// ---------------------------------------------------------------------------
__global__ __launch_bounds__(256) void k1_feat(const float* __restrict__ X,
                                               const float* __restrict__ W,
                                               const float* __restrict__ a,
                                               float* __restrict__ xf,
                                               float* __restrict__ s,
                                               float* __restrict__ t,
                                               float* __restrict__ D) {
    __shared__ float Xs[32 * FF];   // 32 KB
    const int tid  = threadIdx.x;
    const int row0 = blockIdx.x * 32;

    // zero D: 8192 floats = 2048 float4 across blocks 0..7
    {
        const int gid = blockIdx.x * 256 + tid;
        if (gid < NN / 4) ((float4*)D)[gid] = make_float4(0.f, 0.f, 0.f, 0.f);
    }

    const float4* Xg  = (const float4*)(X + (size_t)row0 * FF);
    float4*       Xs4 = (float4*)Xs;
#pragma unroll
    for (int v = 0; v < 8; ++v) Xs4[tid + v * 256] = Xg[tid + v * 256];
    __syncthreads();

    const int f  = tid & 63;   // output feature (lane)
    const int rg = tid >> 6;   // wave id -> rows rg*8 .. rg*8+7

    float acc[8] = {0.f,0.f,0.f,0.f,0.f,0.f,0.f,0.f};
    const float4* Wrow = (const float4*)(W + (size_t)f * FF);
    for (int k4 = 0; k4 < FF / 4; ++k4) {
        float4 wv = Wrow[k4];
#pragma unroll
        for (int r = 0; r < 8; ++r) {
            float4 xv = *(const float4*)&Xs[(rg * 8 + r) * FF + k4 * 4];
            acc[r] = fmaf(wv.x, xv.x, acc[r]);
            acc[r] = fmaf(wv.y, xv.y, acc[r]);
            acc[r] = fmaf(wv.z, xv.z, acc[r]);
            acc[r] = fmaf(wv.w, xv.w, acc[r]);
        }
    }

    const float a0 = a[f];
    const float a1 = a[FF1 + f];
#pragma unroll
    for (int r = 0; r < 8; ++r) {
        const int row = row0 + rg * 8 + r;
        xf[(size_t)row * FF1 + f] = acc[r];
        float vs = acc[r] * a0;
        float vt = acc[r] * a1;
#pragma unroll
        for (int off = 32; off; off >>= 1) {
            vs += __shfl_xor(vs, off);
            vt += __shfl_xor(vt, off);
        }
        if (f == 0) { s[row] = vs; t[row] = vt; }
    }
}

// ---------------------------------------------------------------------------
// kScan: stream A + compact + inline ev/exp + HW f32 atomics into D.
// ---------------------------------------------------------------------------
__global__ __launch_bounds__(256) void kScan(const float* __restrict__ A,
                                             const float* __restrict__ s,
                                             const float* __restrict__ t,
                                             unsigned short* __restrict__ idx,
                                             float* __restrict__ ev,
                                             float* __restrict__ D,
                                             int* __restrict__ counts) {
    const int tid  = threadIdx.x;
    const int lane = tid & 63;
    const int wv   = tid >> 6;
    __shared__ unsigned short lbuf[256 * 8];   // 4 KB private stashes
    __shared__ int wtot[4];

    for (int r = 0; r < 4; ++r) {
        const int i = blockIdx.x * 4 + r;
        int c = 0;
        const float4* Arow = (const float4*)(A + (size_t)i * NN);
#pragma unroll
        for (int k = 0; k < 8; ++k) {
            const int v = tid + k * 256;
            float4 av = Arow[v];
            if (av.x != 0.f) { lbuf[tid * 8 + (c & 7)] = (unsigned short)(4 * v + 0); ++c; }
            if (av.y != 0.f) { lbuf[tid * 8 + (c & 7)] = (unsigned short)(4 * v + 1); ++c; }
            if (av.z != 0.f) { lbuf[tid * 8 + (c & 7)] = (unsigned short)(4 * v + 2); ++c; }
            if (av.w != 0.f) { lbuf[tid * 8 + (c & 7)] = (unsigned short)(4 * v + 3); ++c; }
        }
        if (c > 8) c = 8;   // stash cap (P ~ 1e-13 per thread)

        // inclusive wave scan of c
        int sc = c;
#pragma unroll
        for (int off = 1; off < 64; off <<= 1) {
            int n = __shfl_up(sc, off);
            if (lane >= off) sc += n;
        }
        if (lane == 63) wtot[wv] = sc;
        __syncthreads();

        int base = sc - c;   // exclusive within wave
#pragma unroll
        for (int w = 0; w < 4; ++w) if (w < wv) base += wtot[w];

        const float si = s[i];
        for (int q = 0; q < c; ++q) {
            const int pos = base + q;
            if (pos < CAP) {
                const int j    = lbuf[tid * 8 + q];
                const float x  = si + t[j];
                const float lr = x > 0.f ? x : 0.2f * x;
                const float e  = __expf(lr);
                idx[(size_t)i * CAP + pos] = (unsigned short)j;
                ev [(size_t)i * CAP + pos] = e;
                unsafeAtomicAdd(&D[j], e);
            }
        }
        if (tid == 255) counts[i] = (base + c < CAP) ? (base + c) : CAP;
        __syncthreads();   // protect wtot/lbuf reuse next row
    }
}

// ---------------------------------------------------------------------------
// k3: out[i,:] = sum_p (ev[i,p] / D[idx[i,p]]) * xf[idx[i,p], :]
// ---------------------------------------------------------------------------
__global__ __launch_bounds__(256) void k3_apply(const float* __restrict__ xf,
                                                const float* __restrict__ D,
                                                const unsigned short* __restrict__ idx,
                                                const float* __restrict__ ev,
                                                const int* __restrict__ counts,
                                                float* __restrict__ out) {
    const int wave = threadIdx.x >> 6;
    const int lane = threadIdx.x & 63;
    const int i    = blockIdx.x * 4 + wave;

    const int cnt = counts[i];
    float acc0 = 0.f, acc1 = 0.f, acc2 = 0.f, acc3 = 0.f;

    for (int base = 0; base < cnt; base += 64) {
        const int p = base + lane;
        const bool act = (p < cnt);
        int   jj = act ? (int)idx[(size_t)i * CAP + p] : 0;
        float ww = act ? ev[(size_t)i * CAP + p] / D[jj] : 0.f;

#pragma unroll
        for (int e = 0; e < 64; e += 4) {
            { const int je = __builtin_amdgcn_readlane(jj, e + 0);
              const float we = __int_as_float(__builtin_amdgcn_readlane(__float_as_int(ww), e + 0));
              acc0 = fmaf(we, xf[(size_t)je * FF1 + lane], acc0); }
            { const int je = __builtin_amdgcn_readlane(jj, e + 1);
              const float we = __int_as_float(__builtin_amdgcn_readlane(__float_as_int(ww), e + 1));
              acc1 = fmaf(we, xf[(size_t)je * FF1 + lane], acc1); }
            { const int je = __builtin_amdgcn_readlane(jj, e + 2);
              const float we = __int_as_float(__builtin_amdgcn_readlane(__float_as_int(ww), e + 2));
              acc2 = fmaf(we, xf[(size_t)je * FF1 + lane], acc2); }
            { const int je = __builtin_amdgcn_readlane(jj, e + 3);
              const float we = __int_as_float(__builtin_amdgcn_readlane(__float_as_int(ww), e + 3));
              acc3 = fmaf(we, xf[(size_t)je * FF1 + lane], acc3); }
        }
    }
    out[(size_t)i * FF1 + lane] = (acc0 + acc1) + (acc2 + acc3);
}

// ---------------------------------------------------------------------------
extern "C" void kernel_launch(void* const* d_in, const int* in_sizes, int n_in,
                              void* d_out, int out_size, void* d_ws, size_t ws_size,
                              hipStream_t stream) {
    const float* X = (const float*)d_in[0];   // [N, F]
    const float* A = (const float*)d_in[1];   // [N, N]
    const float* W = (const float*)d_in[2];   // [F1, F]
    const float* a = (const float*)d_in[3];   // [2, F1, 1]
    float* out = (float*)d_out;               // [N, F1]

    // workspace layout
    char* ws = (char*)d_ws;
    float* xf = (float*)ws;                                  ws += (size_t)NN * FF1 * 4;  // 2 MB
    float* s  = (float*)ws;                                  ws += (size_t)NN * 4;        // 32 KB
    float* t  = (float*)ws;                                  ws += (size_t)NN * 4;        // 32 KB
    float* D  = (float*)ws;                                  ws += (size_t)NN * 4;        // 32 KB
    int*   counts = (int*)ws;                                ws += (size_t)NN * 4;        // 32 KB
    unsigned short* idx = (unsigned short*)ws;               ws += (size_t)NN * CAP * 2;  // 4 MB
    float* ev = (float*)ws;                                  // 8 MB

    // ATTRIBUTION: k1 and k3 duplicated (idempotent). Δdur vs 96.5 = k1 + k3.
    k1_feat<<<NN / 32, 256, 0, stream>>>(X, W, a, xf, s, t, D);
    k1_feat<<<NN / 32, 256, 0, stream>>>(X, W, a, xf, s, t, D);
    kScan  <<<NN / 4,  256, 0, stream>>>(A, s, t, idx, ev, D, counts);
    k3_apply<<<NN / 4, 256, 0, stream>>>(xf, D, idx, ev, counts, out);
    k3_apply<<<NN / 4, 256, 0, stream>>>(xf, D, idx, ev, counts, out);
}

// Round 18
// 96.914 us; speedup vs baseline: 1.2128x; 1.2128x over previous
//
#include <hip/hip_runtime.h>
#include <math.h>

#define NN   8192
#define FF   256
#define FF1  64
#define CAP  256   // max edges kept per row (mean 82, std 9 -> 19 sigma)

// ---------------------------------------------------------------------------
// FINAL: R10 configuration (measured optimum, 96.3-96.5us, reproduced).
// Budget (all measured by duplicate-launch attribution):
//   kScan = 58us (44.2 pure A-stream @ ~5.8TB/s + 14 inline edge drain)
//   k1+k3 = 21us;  fixed replay + gaps = ~17.5us.
// k1: xf = X @ W^T;  s = xf@a0;  t = xf@a1;  zero-inits D. 256 blks x 32 rows.
// ---------------------------------------------------------------------------
__global__ __launch_bounds__(256) void k1_feat(const float* __restrict__ X,
                                               const float* __restrict__ W,
                                               const float* __restrict__ a,
                                               float* __restrict__ xf,
                                               float* __restrict__ s,
                                               float* __restrict__ t,
                                               float* __restrict__ D) {
    __shared__ float Xs[32 * FF];   // 32 KB
    const int tid  = threadIdx.x;
    const int row0 = blockIdx.x * 32;

    // zero D: 8192 floats = 2048 float4 across blocks 0..7
    {
        const int gid = blockIdx.x * 256 + tid;
        if (gid < NN / 4) ((float4*)D)[gid] = make_float4(0.f, 0.f, 0.f, 0.f);
    }

    const float4* Xg  = (const float4*)(X + (size_t)row0 * FF);
    float4*       Xs4 = (float4*)Xs;
#pragma unroll
    for (int v = 0; v < 8; ++v) Xs4[tid + v * 256] = Xg[tid + v * 256];
    __syncthreads();

    const int f  = tid & 63;   // output feature (lane)
    const int rg = tid >> 6;   // wave id -> rows rg*8 .. rg*8+7

    float acc[8] = {0.f,0.f,0.f,0.f,0.f,0.f,0.f,0.f};
    const float4* Wrow = (const float4*)(W + (size_t)f * FF);
    for (int k4 = 0; k4 < FF / 4; ++k4) {
        float4 wv = Wrow[k4];
#pragma unroll
        for (int r = 0; r < 8; ++r) {
            float4 xv = *(const float4*)&Xs[(rg * 8 + r) * FF + k4 * 4];
            acc[r] = fmaf(wv.x, xv.x, acc[r]);
            acc[r] = fmaf(wv.y, xv.y, acc[r]);
            acc[r] = fmaf(wv.z, xv.z, acc[r]);
            acc[r] = fmaf(wv.w, xv.w, acc[r]);
        }
    }

    const float a0 = a[f];
    const float a1 = a[FF1 + f];
#pragma unroll
    for (int r = 0; r < 8; ++r) {
        const int row = row0 + rg * 8 + r;
        xf[(size_t)row * FF1 + f] = acc[r];
        float vs = acc[r] * a0;
        float vt = acc[r] * a1;
#pragma unroll
        for (int off = 32; off; off >>= 1) {
            vs += __shfl_xor(vs, off);
            vt += __shfl_xor(vt, off);
        }
        if (f == 0) { s[row] = vs; t[row] = vt; }
    }
}

// ---------------------------------------------------------------------------
// kScan: stream A + compact + inline ev/exp + HW f32 atomics into D.
// ---------------------------------------------------------------------------
__global__ __launch_bounds__(256) void kScan(const float* __restrict__ A,
                                             const float* __restrict__ s,
                                             const float* __restrict__ t,
                                             unsigned short* __restrict__ idx,
                                             float* __restrict__ ev,
                                             float* __restrict__ D,
                                             int* __restrict__ counts) {
    const int tid  = threadIdx.x;
    const int lane = tid & 63;
    const int wv   = tid >> 6;
    __shared__ unsigned short lbuf[256 * 8];   // 4 KB private stashes
    __shared__ int wtot[4];

    for (int r = 0; r < 4; ++r) {
        const int i = blockIdx.x * 4 + r;
        int c = 0;
        const float4* Arow = (const float4*)(A + (size_t)i * NN);
#pragma unroll
        for (int k = 0; k < 8; ++k) {
            const int v = tid + k * 256;
            float4 av = Arow[v];
            if (av.x != 0.f) { lbuf[tid * 8 + (c & 7)] = (unsigned short)(4 * v + 0); ++c; }
            if (av.y != 0.f) { lbuf[tid * 8 + (c & 7)] = (unsigned short)(4 * v + 1); ++c; }
            if (av.z != 0.f) { lbuf[tid * 8 + (c & 7)] = (unsigned short)(4 * v + 2); ++c; }
            if (av.w != 0.f) { lbuf[tid * 8 + (c & 7)] = (unsigned short)(4 * v + 3); ++c; }
        }
        if (c > 8) c = 8;   // stash cap (P ~ 1e-13 per thread)

        // inclusive wave scan of c
        int sc = c;
#pragma unroll
        for (int off = 1; off < 64; off <<= 1) {
            int n = __shfl_up(sc, off);
            if (lane >= off) sc += n;
        }
        if (lane == 63) wtot[wv] = sc;
        __syncthreads();

        int base = sc - c;   // exclusive within wave
#pragma unroll
        for (int w = 0; w < 4; ++w) if (w < wv) base += wtot[w];

        const float si = s[i];
        for (int q = 0; q < c; ++q) {
            const int pos = base + q;
            if (pos < CAP) {
                const int j    = lbuf[tid * 8 + q];
                const float x  = si + t[j];
                const float lr = x > 0.f ? x : 0.2f * x;
                const float e  = __expf(lr);
                idx[(size_t)i * CAP + pos] = (unsigned short)j;
                ev [(size_t)i * CAP + pos] = e;
                unsafeAtomicAdd(&D[j], e);
            }
        }
        if (tid == 255) counts[i] = (base + c < CAP) ? (base + c) : CAP;
        __syncthreads();   // protect wtot/lbuf reuse next row
    }
}

// ---------------------------------------------------------------------------
// k3: out[i,:] = sum_p (ev[i,p] / D[idx[i,p]]) * xf[idx[i,p], :]
// Fixed 64-slot batches, full unroll, readlane -> SGPR broadcast.
// ---------------------------------------------------------------------------
__global__ __launch_bounds__(256) void k3_apply(const float* __restrict__ xf,
                                                const float* __restrict__ D,
                                                const unsigned short* __restrict__ idx,
                                                const float* __restrict__ ev,
                                                const int* __restrict__ counts,
                                                float* __restrict__ out) {
    const int wave = threadIdx.x >> 6;
    const int lane = threadIdx.x & 63;
    const int i    = blockIdx.x * 4 + wave;

    const int cnt = counts[i];
    float acc0 = 0.f, acc1 = 0.f, acc2 = 0.f, acc3 = 0.f;

    for (int base = 0; base < cnt; base += 64) {
        const int p = base + lane;
        const bool act = (p < cnt);
        int   jj = act ? (int)idx[(size_t)i * CAP + p] : 0;
        float ww = act ? ev[(size_t)i * CAP + p] / D[jj] : 0.f;

#pragma unroll
        for (int e = 0; e < 64; e += 4) {
            { const int je = __builtin_amdgcn_readlane(jj, e + 0);
              const float we = __int_as_float(__builtin_amdgcn_readlane(__float_as_int(ww), e + 0));
              acc0 = fmaf(we, xf[(size_t)je * FF1 + lane], acc0); }
            { const int je = __builtin_amdgcn_readlane(jj, e + 1);
              const float we = __int_as_float(__builtin_amdgcn_readlane(__float_as_int(ww), e + 1));
              acc1 = fmaf(we, xf[(size_t)je * FF1 + lane], acc1); }
            { const int je = __builtin_amdgcn_readlane(jj, e + 2);
              const float we = __int_as_float(__builtin_amdgcn_readlane(__float_as_int(ww), e + 2));
              acc2 = fmaf(we, xf[(size_t)je * FF1 + lane], acc2); }
            { const int je = __builtin_amdgcn_readlane(jj, e + 3);
              const float we = __int_as_float(__builtin_amdgcn_readlane(__float_as_int(ww), e + 3));
              acc3 = fmaf(we, xf[(size_t)je * FF1 + lane], acc3); }
        }
    }
    out[(size_t)i * FF1 + lane] = (acc0 + acc1) + (acc2 + acc3);
}

// ---------------------------------------------------------------------------
extern "C" void kernel_launch(void* const* d_in, const int* in_sizes, int n_in,
                              void* d_out, int out_size, void* d_ws, size_t ws_size,
                              hipStream_t stream) {
    const float* X = (const float*)d_in[0];   // [N, F]
    const float* A = (const float*)d_in[1];   // [N, N]
    const float* W = (const float*)d_in[2];   // [F1, F]
    const float* a = (const float*)d_in[3];   // [2, F1, 1]
    float* out = (float*)d_out;               // [N, F1]

    // workspace layout
    char* ws = (char*)d_ws;
    float* xf = (float*)ws;                                  ws += (size_t)NN * FF1 * 4;  // 2 MB
    float* s  = (float*)ws;                                  ws += (size_t)NN * 4;        // 32 KB
    float* t  = (float*)ws;                                  ws += (size_t)NN * 4;        // 32 KB
    float* D  = (float*)ws;                                  ws += (size_t)NN * 4;        // 32 KB
    int*   counts = (int*)ws;                                ws += (size_t)NN * 4;        // 32 KB
    unsigned short* idx = (unsigned short*)ws;               ws += (size_t)NN * CAP * 2;  // 4 MB
    float* ev = (float*)ws;                                  // 8 MB

    k1_feat<<<NN / 32, 256, 0, stream>>>(X, W, a, xf, s, t, D);
    kScan  <<<NN / 4,  256, 0, stream>>>(A, s, t, idx, ev, D, counts);
    k3_apply<<<NN / 4, 256, 0, stream>>>(xf, D, idx, ev, counts, out);
}